// Round 1
// 450.005 us; speedup vs baseline: 1.0223x; 1.0223x over previous
//
#include <hip/hip_runtime.h>
#include <math.h>

// Problem constants
#define BB    128
#define TTW   16
#define FEATN 256
#define NNODE 1024
#define NEDGE 8192
#define MROW  272               // 256 referenced rows + 16 window rows per batch
#define M1    (BB*MROW)         // 34816 rows

// d_out layout (float elements)
#define OUT_MX    0
#define OUT_NODES (BB*TTW*FEATN)
#define OUT_EDGES (OUT_NODES + BB*NNODE*FEATN)
#define OUT_W     (OUT_EDGES + BB*2*NEDGE)
#define OUT_TT    (OUT_W + BB*NEDGE)

// merged-prep thread ranges (after the 128 bucket blocks)
#define R_PASS_END  8388608               // B*1024*64 float4 passthrough+scatter
#define R_WIN_END   (R_PASS_END + 131072) // window rows -> Xc1 bf16
#define R_EDG_END   (R_WIN_END + 524288)  // edges int4 -> float4
#define R_W_END     (R_EDG_END + 262144)  // weights float4 passthrough
#define R_WC_END    (R_W_END + 262144)    // W -> bf16 transposed
#define R_TT_END    (R_WC_END + 128)      // T + taus
#define PREP_BLOCKS (BB + (R_TT_END + 255) / 256)

typedef short bf16x8 __attribute__((ext_vector_type(8)));
typedef float f32x4  __attribute__((ext_vector_type(4)));

__device__ inline unsigned short f2bf(float f) {           // RNE fp32->bf16
    unsigned int u = __float_as_uint(f);
    return (unsigned short)((u + 0x7fffu + ((u >> 16) & 1u)) >> 16);
}
__device__ inline float tanh_fast(float x) {
    return 1.f - 2.f / (__expf(2.f * x) + 1.f);
}

// ---------- fused prep: bucket-sort (blocks 0..127) + all copies/conversions ----------
// blocks [0,128): counting-sort edges by dst (longest-running, dispatched first)
// blocks [128,..): range-dispatched copy work:
//   [0, R_PASS_END)        nodes passthrough + x scatter -> out_nodes, and bf16 -> Xc1 rows<256
//   [R_PASS_END, R_WIN_END) window rows (x) -> Xc1 rows 256..271
//   [R_WIN_END, R_EDG_END)  edges -> float out
//   [R_EDG_END, R_W_END)    weights -> float out
//   [R_W_END, R_WC_END)     W -> bf16 transposed [n][k]
//   [R_WC_END, R_TT_END)    T + taus
__global__ void k_prep(const float* __restrict__ x, const int* __restrict__ taus,
                       const float* __restrict__ nodes, const int* __restrict__ edges,
                       const float* __restrict__ weights, const int* __restrict__ T,
                       const float* __restrict__ Ws1, const float* __restrict__ Wm1,
                       const float* __restrict__ Ws2, const float* __restrict__ Wm2,
                       float* __restrict__ out, unsigned short* __restrict__ Xc1,
                       unsigned short* __restrict__ Wt1, unsigned short* __restrict__ Wt2,
                       int2* __restrict__ sw, int* __restrict__ bstart) {
    __shared__ int cnt[256];
    __shared__ int pos[256];
    if (blockIdx.x < BB) {
        // ---- counting-sort edges by dst for batch b (feeds spmm1 + agg2) ----
        int b = blockIdx.x, tid = threadIdx.x;
        cnt[tid] = 0;
        __syncthreads();
        const int* src = edges + (size_t)b * 2 * NEDGE;
        const int* dst = src + NEDGE;
        for (int e = tid; e < NEDGE; e += 256) atomicAdd(&cnt[dst[e]], 1);
        __syncthreads();
        int my = cnt[tid], v = my;
        for (int off = 1; off < 256; off <<= 1) {
            int u = 0;
            if (tid >= off) u = cnt[tid - off];
            __syncthreads();
            cnt[tid] = v = v + u;
            __syncthreads();
        }
        int start = v - my;
        bstart[b * 264 + tid] = start;
        if (tid == 0) bstart[b * 264 + 256] = NEDGE;
        pos[tid] = start;
        __syncthreads();
        const float* wb = weights + (size_t)b * NEDGE;
        for (int e = tid; e < NEDGE; e += 256) {
            int d = dst[e];
            int p = atomicAdd(&pos[d], 1);
            sw[(size_t)b * NEDGE + p] = make_int2(src[e], __float_as_int(wb[e]));
        }
        return;
    }

    int idx = (blockIdx.x - BB) * 256 + threadIdx.x;
    if (idx < R_PASS_END) {
        // nodes passthrough with x scatter; rows<256 also emit bf16 into Xc1
        int b = idx >> 16, row = (idx >> 6) & 1023, f = idx & 63;
        int dT = row - T[b];
        const float4* src = ((unsigned)dT < 16u)
                                ? ((const float4*)x + ((size_t)b * 16 + dT) * 64 + f)
                                : ((const float4*)nodes + idx);
        float4 v = *src;
        ((float4*)(out + OUT_NODES))[idx] = v;
        if (row < 256) {
            uint2 p;
            p.x = f2bf(v.x) | ((unsigned)f2bf(v.y) << 16);
            p.y = f2bf(v.z) | ((unsigned)f2bf(v.w) << 16);
            *(uint2*)(Xc1 + ((size_t)(b * MROW + row)) * 512 + f * 4) = p;
        }
    } else if (idx < R_WIN_END) {
        int j = idx - R_PASS_END;            // b(7) | i(4) | f(6)
        int b = j >> 10, i = (j >> 6) & 15, f = j & 63;
        float4 v = ((const float4*)x)[((size_t)b * 16 + i) * 64 + f];
        uint2 p;
        p.x = f2bf(v.x) | ((unsigned)f2bf(v.y) << 16);
        p.y = f2bf(v.z) | ((unsigned)f2bf(v.w) << 16);
        *(uint2*)(Xc1 + ((size_t)(b * MROW + 256 + i)) * 512 + f * 4) = p;
    } else if (idx < R_EDG_END) {
        int j = idx - R_WIN_END;
        int4 e = ((const int4*)edges)[j];
        ((float4*)(out + OUT_EDGES))[j] =
            make_float4((float)e.x, (float)e.y, (float)e.z, (float)e.w);
    } else if (idx < R_W_END) {
        int j = idx - R_EDG_END;
        ((float4*)(out + OUT_W))[j] = ((const float4*)weights)[j];
    } else if (idx < R_WC_END) {
        int j = idx - R_W_END;
        int layer = j >> 17, q = j & 131071;
        int k = q >> 8, n = q & 255;
        const float* Ws = layer ? Ws2 : Ws1;
        const float* Wm = layer ? Wm2 : Wm1;
        float v = (k < 256) ? Ws[(size_t)k * 256 + n] : Wm[(size_t)(k - 256) * 256 + n];
        (layer ? Wt2 : Wt1)[(size_t)n * 512 + k] = f2bf(v);
    } else if (idx < R_TT_END) {
        int b = idx - R_WC_END;
        out[OUT_TT + b] = (float)(T[b] + taus[b]);
    }
}

// ---------- layer-1 aggregation as bucketed SpMM: Xc1[:,256:512] = Agg ----------
// one wave per output row (272 per batch); window rows (r>=256) use dst=T+i
// (zero if T+i>=256) -- folds the old k_zero/k_adj/k_aggemm/k_xt/k_fixwin.
// reads: per-batch X half (131 KB bf16, L2-resident) gathered per edge.
__global__ void k_spmm1(const int2* __restrict__ sw, const int* __restrict__ bstart,
                        const int* __restrict__ T, unsigned short* __restrict__ Xc1) {
    int g    = blockIdx.x * 4 + (threadIdx.x >> 6);   // 0..34815
    int lane = threadIdx.x & 63;
    int b = g / MROW;
    int r = g - b * MROW;
    int d = (r < 256) ? r : (T[b] + r - 256);
    float4 acc = make_float4(0.f, 0.f, 0.f, 0.f);
    if (d < 256) {
        int e0 = bstart[b * 264 + d];
        int e1 = bstart[b * 264 + d + 1];
        const int2* swb = sw + (size_t)b * NEDGE;
        const unsigned short* xb = Xc1 + (size_t)b * MROW * 512;
        for (int e = e0; e < e1; ++e) {
            int2 p = swb[e];
            float wt = __int_as_float(p.y);
            uint2 q = *((const uint2*)(xb + (size_t)p.x * 512) + lane);
            acc.x = fmaf(wt, __uint_as_float(q.x << 16),          acc.x);
            acc.y = fmaf(wt, __uint_as_float(q.x & 0xffff0000u),  acc.y);
            acc.z = fmaf(wt, __uint_as_float(q.y << 16),          acc.z);
            acc.w = fmaf(wt, __uint_as_float(q.y & 0xffff0000u),  acc.w);
        }
    }
    uint2 o;
    o.x = f2bf(acc.x) | ((unsigned)f2bf(acc.y) << 16);
    o.y = f2bf(acc.z) | ((unsigned)f2bf(acc.w) << 16);
    *(uint2*)(Xc1 + (size_t)g * 512 + 256 + lane * 4) = o;
}

// ---------- MFMA GEMM: out = tanh(Xc[M][512] @ Wt^T) ----------
template <int OBF16>
__global__ __launch_bounds__(256, 2) void k_gemm(const unsigned short* __restrict__ Xc,
                                                 const unsigned short* __restrict__ Wt,
                                                 void* __restrict__ outp) {
    int tile_m = blockIdx.x >> 1;
    int tile_n = blockIdx.x & 1;
    int tid  = threadIdx.x;
    int wv   = tid >> 6, lane = tid & 63;
    int wm   = wv >> 1, wn = wv & 1;
    int lm   = lane & 15, lq = lane >> 4;

    __shared__ short As[128 * 32];
    __shared__ short Bs[128 * 32];

    f32x4 acc[4][4];
#pragma unroll
    for (int mi = 0; mi < 4; ++mi)
#pragma unroll
        for (int ni = 0; ni < 4; ++ni) acc[mi][ni] = (f32x4){0.f, 0.f, 0.f, 0.f};

    for (int kc = 0; kc < 16; ++kc) {
        if (kc) __syncthreads();
#pragma unroll
        for (int p = 0; p < 2; ++p) {
            int slot = p * 256 + tid;
            int row = slot >> 2, seg = slot & 3;
            ((uint4*)As)[slot] = *(const uint4*)(Xc + ((size_t)(tile_m * 128 + row)) * 512 + kc * 32 + seg * 8);
            ((uint4*)Bs)[slot] = *(const uint4*)(Wt + ((size_t)(tile_n * 128 + row)) * 512 + kc * 32 + seg * 8);
        }
        __syncthreads();

        bf16x8 af[4], bfr[4];
#pragma unroll
        for (int mi = 0; mi < 4; ++mi)
            af[mi] = ((const bf16x8*)As)[(wm * 64 + mi * 16 + lm) * 4 + lq];
#pragma unroll
        for (int ni = 0; ni < 4; ++ni)
            bfr[ni] = ((const bf16x8*)Bs)[(wn * 64 + ni * 16 + lm) * 4 + lq];
#pragma unroll
        for (int mi = 0; mi < 4; ++mi)
#pragma unroll
            for (int ni = 0; ni < 4; ++ni)
                acc[mi][ni] = __builtin_amdgcn_mfma_f32_16x16x32_bf16(af[mi], bfr[ni], acc[mi][ni], 0, 0, 0);
    }

#pragma unroll
    for (int mi = 0; mi < 4; ++mi) {
#pragma unroll
        for (int ni = 0; ni < 4; ++ni) {
            int n = tile_n * 128 + wn * 64 + ni * 16 + lm;
#pragma unroll
            for (int r = 0; r < 4; ++r) {
                int m = tile_m * 128 + wm * 64 + mi * 16 + lq * 4 + r;
                float v = tanh_fast(acc[mi][ni][r]);
                if (OBF16) ((unsigned short*)outp)[(size_t)m * 256 + n] = f2bf(v);
                else       ((float*)outp)[(size_t)m * 256 + n] = v;
            }
        }
    }
}

// ---------- agg2 + build Xcat2 (window rows only) ----------
__global__ void k_agg2(const unsigned short* __restrict__ h1, const int2* __restrict__ sw,
                       const int* __restrict__ bstart, const int* __restrict__ T,
                       unsigned short* __restrict__ Xc2) {
    int g2   = blockIdx.x * 4 + (threadIdx.x >> 6);
    int lane = threadIdx.x & 63;
    int b = g2 >> 4, i = g2 & 15;
    ((uint2*)(Xc2 + (size_t)g2 * 512))[lane] =
        ((const uint2*)(h1 + (size_t)(b * MROW + 256 + i) * 256))[lane];
    int d = T[b] + i;
    float4 acc = make_float4(0.f, 0.f, 0.f, 0.f);
    if (d < 256) {
        int e0 = bstart[b * 264 + d];
        int e1 = bstart[b * 264 + d + 1];
        const int2* swb = sw + (size_t)b * NEDGE;
        const unsigned short* hb = h1 + (size_t)b * MROW * 256;
        for (int e = e0; e < e1; ++e) {
            int2 p = swb[e];
            float wt = __int_as_float(p.y);
            uint2 q = *((const uint2*)(hb + (size_t)p.x * 256) + lane);
            acc.x = fmaf(wt, __uint_as_float(q.x << 16),          acc.x);
            acc.y = fmaf(wt, __uint_as_float(q.x & 0xffff0000u),  acc.y);
            acc.z = fmaf(wt, __uint_as_float(q.y << 16),          acc.z);
            acc.w = fmaf(wt, __uint_as_float(q.y & 0xffff0000u),  acc.w);
        }
    }
    uint2 o;
    o.x = f2bf(acc.x) | ((unsigned)f2bf(acc.y) << 16);
    o.y = f2bf(acc.z) | ((unsigned)f2bf(acc.w) << 16);
    *(uint2*)(Xc2 + (size_t)g2 * 512 + 256 + lane * 4) = o;
}

// ---------- launcher ----------
extern "C" void kernel_launch(void* const* d_in, const int* in_sizes, int n_in,
                              void* d_out, int out_size, void* d_ws, size_t ws_size,
                              hipStream_t stream) {
    const float* x       = (const float*)d_in[0];
    const int*   taus    = (const int*)d_in[1];
    const float* nodes   = (const float*)d_in[2];
    const int*   edges   = (const int*)d_in[3];
    const float* weights = (const float*)d_in[4];
    const int*   T       = (const int*)d_in[5];
    const float* Ws1     = (const float*)d_in[6];
    const float* Wm1     = (const float*)d_in[7];
    const float* Ws2     = (const float*)d_in[8];
    const float* Wm2     = (const float*)d_in[9];
    float* out = (float*)d_out;

    // workspace layout (bytes) -- dense-adjacency buffers (W_adj, Xt) removed
    char* ws = (char*)d_ws;
    int2*           sw     = (int2*)ws;                              //  8,388,608
    int*            bstart = (int*)(ws + 8388608);                   //    135,168
    unsigned short* Xc1    = (unsigned short*)(ws + 8523776);        // 35,651,584  [34816][512]
    unsigned short* h1     = (unsigned short*)(ws + 44175360);       // 17,825,792  [34816][256]
    unsigned short* Xc2    = (unsigned short*)(ws + 62001152);       //  2,097,152  [2048][512]
    unsigned short* Wt1    = (unsigned short*)(ws + 64098304);       //    262,144
    unsigned short* Wt2    = (unsigned short*)(ws + 64360448);       //    262,144

    k_prep  <<<PREP_BLOCKS, 256, 0, stream>>>(x, taus, nodes, edges, weights, T,
                                              Ws1, Wm1, Ws2, Wm2,
                                              out, Xc1, Wt1, Wt2, sw, bstart);
    k_spmm1 <<<M1 / 4, 256, 0, stream>>>(sw, bstart, T, Xc1);
    k_gemm<1><<<272 * 2, 256, 0, stream>>>(Xc1, Wt1, h1);
    k_agg2  <<<512, 256, 0, stream>>>(h1, sw, bstart, T, Xc2);
    k_gemm<0><<<16 * 2, 256, 0, stream>>>(Xc2, Wt2, out + OUT_MX);
}

// Round 3
// 377.066 us; speedup vs baseline: 1.2200x; 1.1934x over previous
//
#include <hip/hip_runtime.h>
#include <math.h>

// Problem constants
#define BB    128
#define TTW   16
#define FEATN 256
#define NNODE 1024
#define NEDGE 8192
#define MROW  272               // 256 referenced rows + 16 window rows per batch
#define M1    (BB*MROW)         // 34816 rows

// d_out layout (float elements)
#define OUT_MX    0
#define OUT_NODES (BB*TTW*FEATN)
#define OUT_EDGES (OUT_NODES + BB*NNODE*FEATN)
#define OUT_W     (OUT_EDGES + BB*2*NEDGE)
#define OUT_TT    (OUT_W + BB*NEDGE)

// merged-prep thread ranges (after the 128 bucket blocks)
#define R_PASS_END  8388608               // B*1024*64 float4 passthrough+scatter
#define R_WIN_END   (R_PASS_END + 131072) // window rows -> Xc1 bf16
#define R_EDG_END   (R_WIN_END + 524288)  // edges int4 -> float4
#define R_W_END     (R_EDG_END + 262144)  // weights float4 passthrough
#define R_WC_END    (R_W_END + 262144)    // W -> bf16 transposed
#define R_TT_END    (R_WC_END + 128)      // T + taus
#define PREP_BLOCKS (BB + (R_TT_END + 255) / 256)

typedef short bf16x8 __attribute__((ext_vector_type(8)));
typedef float f32x4  __attribute__((ext_vector_type(4)));

__device__ inline unsigned short f2bf(float f) {           // RNE fp32->bf16
    unsigned int u = __float_as_uint(f);
    return (unsigned short)((u + 0x7fffu + ((u >> 16) & 1u)) >> 16);
}
__device__ inline float tanh_fast(float x) {
    return 1.f - 2.f / (__expf(2.f * x) + 1.f);
}
// async global->LDS, 16B per lane. LDS dest = wave-uniform base + lane*16.
__device__ inline void gl_lds16(const unsigned short* g, short* l) {
    __builtin_amdgcn_global_load_lds((const __attribute__((address_space(1))) void*)g,
                                     (__attribute__((address_space(3))) void*)l, 16, 0, 0);
}

// ---------- fused prep: bucket-sort (blocks 0..127) + all copies/conversions ----------
__global__ void k_prep(const float* __restrict__ x, const int* __restrict__ taus,
                       const float* __restrict__ nodes, const int* __restrict__ edges,
                       const float* __restrict__ weights, const int* __restrict__ T,
                       const float* __restrict__ Ws1, const float* __restrict__ Wm1,
                       const float* __restrict__ Ws2, const float* __restrict__ Wm2,
                       float* __restrict__ out, unsigned short* __restrict__ Xc1,
                       unsigned short* __restrict__ Wt1, unsigned short* __restrict__ Wt2,
                       int2* __restrict__ sw, int* __restrict__ bstart) {
    __shared__ int cnt[256];
    __shared__ int pos[256];
    if (blockIdx.x < BB) {
        // ---- counting-sort edges by dst for batch b (feeds spmm1 + agg2) ----
        int b = blockIdx.x, tid = threadIdx.x;
        cnt[tid] = 0;
        __syncthreads();
        const int* src = edges + (size_t)b * 2 * NEDGE;
        const int* dst = src + NEDGE;
        for (int e = tid; e < NEDGE; e += 256) atomicAdd(&cnt[dst[e]], 1);
        __syncthreads();
        int my = cnt[tid], v = my;
        for (int off = 1; off < 256; off <<= 1) {
            int u = 0;
            if (tid >= off) u = cnt[tid - off];
            __syncthreads();
            cnt[tid] = v = v + u;
            __syncthreads();
        }
        int start = v - my;
        bstart[b * 264 + tid] = start;
        if (tid == 0) bstart[b * 264 + 256] = NEDGE;
        pos[tid] = start;
        __syncthreads();
        const float* wb = weights + (size_t)b * NEDGE;
        for (int e = tid; e < NEDGE; e += 256) {
            int d = dst[e];
            int p = atomicAdd(&pos[d], 1);
            sw[(size_t)b * NEDGE + p] = make_int2(src[e], __float_as_int(wb[e]));
        }
        return;
    }

    int idx = (blockIdx.x - BB) * 256 + threadIdx.x;
    if (idx < R_PASS_END) {
        // nodes passthrough with x scatter; rows<256 also emit bf16 into Xc1
        int b = idx >> 16, row = (idx >> 6) & 1023, f = idx & 63;
        int dT = row - T[b];
        f32x4 v;
        if ((unsigned)dT < 16u) v = ((const f32x4*)x)[((size_t)b * 16 + dT) * 64 + f];
        else                    v = __builtin_nontemporal_load((const f32x4*)nodes + idx);
        __builtin_nontemporal_store(v, (f32x4*)(out + OUT_NODES) + idx);
        if (row < 256) {
            uint2 p;
            p.x = f2bf(v.x) | ((unsigned)f2bf(v.y) << 16);
            p.y = f2bf(v.z) | ((unsigned)f2bf(v.w) << 16);
            *(uint2*)(Xc1 + ((size_t)(b * MROW + row)) * 512 + f * 4) = p;
        }
    } else if (idx < R_WIN_END) {
        int j = idx - R_PASS_END;            // b(7) | i(4) | f(6)
        int b = j >> 10, i = (j >> 6) & 15, f = j & 63;
        f32x4 v = ((const f32x4*)x)[((size_t)b * 16 + i) * 64 + f];
        uint2 p;
        p.x = f2bf(v.x) | ((unsigned)f2bf(v.y) << 16);
        p.y = f2bf(v.z) | ((unsigned)f2bf(v.w) << 16);
        *(uint2*)(Xc1 + ((size_t)(b * MROW + 256 + i)) * 512 + f * 4) = p;
    } else if (idx < R_EDG_END) {
        int j = idx - R_WIN_END;
        int4 e = ((const int4*)edges)[j];
        f32x4 o;
        o.x = (float)e.x; o.y = (float)e.y; o.z = (float)e.z; o.w = (float)e.w;
        __builtin_nontemporal_store(o, (f32x4*)(out + OUT_EDGES) + j);
    } else if (idx < R_W_END) {
        int j = idx - R_EDG_END;
        f32x4 v = __builtin_nontemporal_load((const f32x4*)weights + j);
        __builtin_nontemporal_store(v, (f32x4*)(out + OUT_W) + j);
    } else if (idx < R_WC_END) {
        int j = idx - R_W_END;
        int layer = j >> 17, q = j & 131071;
        int k = q >> 8, n = q & 255;
        const float* Ws = layer ? Ws2 : Ws1;
        const float* Wm = layer ? Wm2 : Wm1;
        float v = (k < 256) ? Ws[(size_t)k * 256 + n] : Wm[(size_t)(k - 256) * 256 + n];
        (layer ? Wt2 : Wt1)[(size_t)n * 512 + k] = f2bf(v);
    } else if (idx < R_TT_END) {
        int b = idx - R_WC_END;
        out[OUT_TT + b] = (float)(T[b] + taus[b]);
    }
}

// ---------- layer-1 aggregation as bucketed SpMM: Xc1[:,256:512] = Agg ----------
// one wave per output row; XCD-swizzled so batch b's 68 blocks land on XCD b%8
// (per-XCD working set ~5 MB -> gathers are L2-local, not L3).
// Edge metadata is lane-cooperatively prefetched (64 entries/load) and broadcast
// via v_readlane (scalar); 4 gathers kept in flight to hide L2 latency.
__global__ void k_spmm1(const int2* __restrict__ sw, const int* __restrict__ bstart,
                        const int* __restrict__ T, unsigned short* __restrict__ Xc1) {
    int p = blockIdx.x;
    int inner = p >> 3;
    int b = (inner / 68) * 8 + (p & 7);
    int r = (inner % 68) * 4 + (threadIdx.x >> 6);
    int lane = threadIdx.x & 63;
    int g = b * MROW + r;
    int d = (r < 256) ? r : (T[b] + r - 256);
    float4 acc = make_float4(0.f, 0.f, 0.f, 0.f);
    if (d < 256) {
        int e0 = bstart[b * 264 + d];
        int e1 = bstart[b * 264 + d + 1];
        const int2* swb = sw + (size_t)b * NEDGE;
        const unsigned short* xb = Xc1 + (size_t)b * MROW * 512;
        for (int ce = e0; ce < e1; ce += 64) {
            int2 pl = (ce + lane < e1) ? swb[ce + lane] : make_int2(0, 0);
            int cnt = e1 - ce; if (cnt > 64) cnt = 64;
            for (int i = 0; i < cnt; i += 4) {
                int x0 = __builtin_amdgcn_readlane(pl.x, i + 0);
                int y0 = __builtin_amdgcn_readlane(pl.y, i + 0);
                int x1 = __builtin_amdgcn_readlane(pl.x, i + 1);
                int y1 = __builtin_amdgcn_readlane(pl.y, i + 1);
                int x2 = __builtin_amdgcn_readlane(pl.x, i + 2);
                int y2 = __builtin_amdgcn_readlane(pl.y, i + 2);
                int x3 = __builtin_amdgcn_readlane(pl.x, i + 3);
                int y3 = __builtin_amdgcn_readlane(pl.y, i + 3);
                uint2 q0 = *((const uint2*)(xb + (size_t)x0 * 512) + lane);
                uint2 q1 = *((const uint2*)(xb + (size_t)x1 * 512) + lane);
                uint2 q2 = *((const uint2*)(xb + (size_t)x2 * 512) + lane);
                uint2 q3 = *((const uint2*)(xb + (size_t)x3 * 512) + lane);
                float w0 = __int_as_float(y0), w1 = __int_as_float(y1);
                float w2 = __int_as_float(y2), w3 = __int_as_float(y3);
                acc.x = fmaf(w0, __uint_as_float(q0.x << 16),         acc.x);
                acc.y = fmaf(w0, __uint_as_float(q0.x & 0xffff0000u), acc.y);
                acc.z = fmaf(w0, __uint_as_float(q0.y << 16),         acc.z);
                acc.w = fmaf(w0, __uint_as_float(q0.y & 0xffff0000u), acc.w);
                acc.x = fmaf(w1, __uint_as_float(q1.x << 16),         acc.x);
                acc.y = fmaf(w1, __uint_as_float(q1.x & 0xffff0000u), acc.y);
                acc.z = fmaf(w1, __uint_as_float(q1.y << 16),         acc.z);
                acc.w = fmaf(w1, __uint_as_float(q1.y & 0xffff0000u), acc.w);
                acc.x = fmaf(w2, __uint_as_float(q2.x << 16),         acc.x);
                acc.y = fmaf(w2, __uint_as_float(q2.x & 0xffff0000u), acc.y);
                acc.z = fmaf(w2, __uint_as_float(q2.y << 16),         acc.z);
                acc.w = fmaf(w2, __uint_as_float(q2.y & 0xffff0000u), acc.w);
                acc.x = fmaf(w3, __uint_as_float(q3.x << 16),         acc.x);
                acc.y = fmaf(w3, __uint_as_float(q3.x & 0xffff0000u), acc.y);
                acc.z = fmaf(w3, __uint_as_float(q3.y << 16),         acc.z);
                acc.w = fmaf(w3, __uint_as_float(q3.y & 0xffff0000u), acc.w);
            }
        }
    }
    uint2 o;
    o.x = f2bf(acc.x) | ((unsigned)f2bf(acc.y) << 16);
    o.y = f2bf(acc.z) | ((unsigned)f2bf(acc.w) << 16);
    *(uint2*)(Xc1 + (size_t)g * 512 + 256 + lane * 4) = o;
}

// ---------- MFMA GEMM: out = tanh(Xc[M][512] @ Wt^T), global_load_lds staging ----------
template <int OBF16>
__global__ __launch_bounds__(256, 2) void k_gemm(const unsigned short* __restrict__ Xc,
                                                 const unsigned short* __restrict__ Wt,
                                                 void* __restrict__ outp) {
    int tile_m = blockIdx.x >> 1;
    int tile_n = blockIdx.x & 1;
    int tid  = threadIdx.x;
    int wv   = tid >> 6, lane = tid & 63;
    int wm   = wv >> 1, wn = wv & 1;
    int lm   = lane & 15, lq = lane >> 4;

    __shared__ short As[128 * 32];
    __shared__ short Bs[128 * 32];

    f32x4 acc[4][4];
#pragma unroll
    for (int mi = 0; mi < 4; ++mi)
#pragma unroll
        for (int ni = 0; ni < 4; ++ni) acc[mi][ni] = (f32x4){0.f, 0.f, 0.f, 0.f};

    // staging geometry: wave wv covers rows [wv*32, wv*32+32) in two 16-row chunks.
    // lane l -> row +(l>>2), 16B seg (l&3). LDS chunk base = (wv*2+j)*512 shorts;
    // HW writes base + lane*16 which is exactly row-major [128][32] bf16.
    const unsigned short* Ag = Xc + (size_t)(tile_m * 128 + wv * 32 + (lane >> 2)) * 512 + (lane & 3) * 8;
    const unsigned short* Bg = Wt + (size_t)(tile_n * 128 + wv * 32 + (lane >> 2)) * 512 + (lane & 3) * 8;
    short* Al = As + (wv * 2) * 512 + lane * 8;
    short* Bl = Bs + (wv * 2) * 512 + lane * 8;

    for (int kc = 0; kc < 16; ++kc) {
        if (kc) __syncthreads();
        gl_lds16(Ag + kc * 32,              Al);
        gl_lds16(Ag + kc * 32 + 16 * 512,   Al + 512);
        gl_lds16(Bg + kc * 32,              Bl);
        gl_lds16(Bg + kc * 32 + 16 * 512,   Bl + 512);
        __syncthreads();

        bf16x8 af[4], bfr[4];
#pragma unroll
        for (int mi = 0; mi < 4; ++mi)
            af[mi] = ((const bf16x8*)As)[(wm * 64 + mi * 16 + lm) * 4 + lq];
#pragma unroll
        for (int ni = 0; ni < 4; ++ni)
            bfr[ni] = ((const bf16x8*)Bs)[(wn * 64 + ni * 16 + lm) * 4 + lq];
#pragma unroll
        for (int mi = 0; mi < 4; ++mi)
#pragma unroll
            for (int ni = 0; ni < 4; ++ni)
                acc[mi][ni] = __builtin_amdgcn_mfma_f32_16x16x32_bf16(af[mi], bfr[ni], acc[mi][ni], 0, 0, 0);
    }

#pragma unroll
    for (int mi = 0; mi < 4; ++mi) {
#pragma unroll
        for (int ni = 0; ni < 4; ++ni) {
            int n = tile_n * 128 + wn * 64 + ni * 16 + lm;
#pragma unroll
            for (int r = 0; r < 4; ++r) {
                int m = tile_m * 128 + wm * 64 + mi * 16 + lq * 4 + r;
                float v = tanh_fast(acc[mi][ni][r]);
                if (OBF16) ((unsigned short*)outp)[(size_t)m * 256 + n] = f2bf(v);
                else       ((float*)outp)[(size_t)m * 256 + n] = v;
            }
        }
    }
}

// ---------- agg2 + build Xcat2 (window rows only) ----------
// XCD-swizzled (batch b -> XCD b%8); readlane broadcast + 4 gathers in flight.
__global__ void k_agg2(const unsigned short* __restrict__ h1, const int2* __restrict__ sw,
                       const int* __restrict__ bstart, const int* __restrict__ T,
                       unsigned short* __restrict__ Xc2) {
    int p = blockIdx.x;
    int inner = p >> 3;
    int b = (inner / 4) * 8 + (p & 7);
    int i = (inner % 4) * 4 + (threadIdx.x >> 6);
    int lane = threadIdx.x & 63;
    int g2 = b * 16 + i;
    ((uint2*)(Xc2 + (size_t)g2 * 512))[lane] =
        ((const uint2*)(h1 + (size_t)(b * MROW + 256 + i) * 256))[lane];
    int d = T[b] + i;
    float4 acc = make_float4(0.f, 0.f, 0.f, 0.f);
    if (d < 256) {
        int e0 = bstart[b * 264 + d];
        int e1 = bstart[b * 264 + d + 1];
        const int2* swb = sw + (size_t)b * NEDGE;
        const unsigned short* hb = h1 + (size_t)b * MROW * 256;
        for (int ce = e0; ce < e1; ce += 64) {
            int2 pl = (ce + lane < e1) ? swb[ce + lane] : make_int2(0, 0);
            int cnt = e1 - ce; if (cnt > 64) cnt = 64;
            for (int ii = 0; ii < cnt; ii += 4) {
                int x0 = __builtin_amdgcn_readlane(pl.x, ii + 0);
                int y0 = __builtin_amdgcn_readlane(pl.y, ii + 0);
                int x1 = __builtin_amdgcn_readlane(pl.x, ii + 1);
                int y1 = __builtin_amdgcn_readlane(pl.y, ii + 1);
                int x2 = __builtin_amdgcn_readlane(pl.x, ii + 2);
                int y2 = __builtin_amdgcn_readlane(pl.y, ii + 2);
                int x3 = __builtin_amdgcn_readlane(pl.x, ii + 3);
                int y3 = __builtin_amdgcn_readlane(pl.y, ii + 3);
                uint2 q0 = *((const uint2*)(hb + (size_t)x0 * 256) + lane);
                uint2 q1 = *((const uint2*)(hb + (size_t)x1 * 256) + lane);
                uint2 q2 = *((const uint2*)(hb + (size_t)x2 * 256) + lane);
                uint2 q3 = *((const uint2*)(hb + (size_t)x3 * 256) + lane);
                float w0 = __int_as_float(y0), w1 = __int_as_float(y1);
                float w2 = __int_as_float(y2), w3 = __int_as_float(y3);
                acc.x = fmaf(w0, __uint_as_float(q0.x << 16),         acc.x);
                acc.y = fmaf(w0, __uint_as_float(q0.x & 0xffff0000u), acc.y);
                acc.z = fmaf(w0, __uint_as_float(q0.y << 16),         acc.z);
                acc.w = fmaf(w0, __uint_as_float(q0.y & 0xffff0000u), acc.w);
                acc.x = fmaf(w1, __uint_as_float(q1.x << 16),         acc.x);
                acc.y = fmaf(w1, __uint_as_float(q1.x & 0xffff0000u), acc.y);
                acc.z = fmaf(w1, __uint_as_float(q1.y << 16),         acc.z);
                acc.w = fmaf(w1, __uint_as_float(q1.y & 0xffff0000u), acc.w);
                acc.x = fmaf(w2, __uint_as_float(q2.x << 16),         acc.x);
                acc.y = fmaf(w2, __uint_as_float(q2.x & 0xffff0000u), acc.y);
                acc.z = fmaf(w2, __uint_as_float(q2.y << 16),         acc.z);
                acc.w = fmaf(w2, __uint_as_float(q2.y & 0xffff0000u), acc.w);
                acc.x = fmaf(w3, __uint_as_float(q3.x << 16),         acc.x);
                acc.y = fmaf(w3, __uint_as_float(q3.x & 0xffff0000u), acc.y);
                acc.z = fmaf(w3, __uint_as_float(q3.y << 16),         acc.z);
                acc.w = fmaf(w3, __uint_as_float(q3.y & 0xffff0000u), acc.w);
            }
        }
    }
    uint2 o;
    o.x = f2bf(acc.x) | ((unsigned)f2bf(acc.y) << 16);
    o.y = f2bf(acc.z) | ((unsigned)f2bf(acc.w) << 16);
    *(uint2*)(Xc2 + (size_t)g2 * 512 + 256 + lane * 4) = o;
}

// ---------- launcher ----------
extern "C" void kernel_launch(void* const* d_in, const int* in_sizes, int n_in,
                              void* d_out, int out_size, void* d_ws, size_t ws_size,
                              hipStream_t stream) {
    const float* x       = (const float*)d_in[0];
    const int*   taus    = (const int*)d_in[1];
    const float* nodes   = (const float*)d_in[2];
    const int*   edges   = (const int*)d_in[3];
    const float* weights = (const float*)d_in[4];
    const int*   T       = (const int*)d_in[5];
    const float* Ws1     = (const float*)d_in[6];
    const float* Wm1     = (const float*)d_in[7];
    const float* Ws2     = (const float*)d_in[8];
    const float* Wm2     = (const float*)d_in[9];
    float* out = (float*)d_out;

    // workspace layout (bytes)
    char* ws = (char*)d_ws;
    int2*           sw     = (int2*)ws;                              //  8,388,608
    int*            bstart = (int*)(ws + 8388608);                   //    135,168
    unsigned short* Xc1    = (unsigned short*)(ws + 8523776);        // 35,651,584  [34816][512]
    unsigned short* h1     = (unsigned short*)(ws + 44175360);       // 17,825,792  [34816][256]
    unsigned short* Xc2    = (unsigned short*)(ws + 62001152);       //  2,097,152  [2048][512]
    unsigned short* Wt1    = (unsigned short*)(ws + 64098304);       //    262,144
    unsigned short* Wt2    = (unsigned short*)(ws + 64360448);       //    262,144

    k_prep  <<<PREP_BLOCKS, 256, 0, stream>>>(x, taus, nodes, edges, weights, T,
                                              Ws1, Wm1, Ws2, Wm2,
                                              out, Xc1, Wt1, Wt2, sw, bstart);
    k_spmm1 <<<M1 / 4, 256, 0, stream>>>(sw, bstart, T, Xc1);
    k_gemm<1><<<272 * 2, 256, 0, stream>>>(Xc1, Wt1, h1);
    k_agg2  <<<512, 256, 0, stream>>>(h1, sw, bstart, T, Xc2);
    k_gemm<0><<<16 * 2, 256, 0, stream>>>(Xc2, Wt2, out + OUT_MX);
}